// Round 3
// baseline (38600.748 us; speedup 1.0000x reference)
//
#include <hip/hip_runtime.h>
#include <hip/hip_fp16.h>
#include <stdint.h>

#define TIME_STEPS 4096
#define DIM        2048
#define NWG        128
#define NTH        256
#define NWAVE      ((NWG * NTH) / 64)   // 512 waves, 4 rows each
#define RPW        4

// actbuf entry: u32 = (gen_tag16 << 16) | fp16bits(act).  Slot t%NSLOT holds
// gen t (tag t+1).  With NSLOT==TIME_STEPS there is no reuse -> no WAR gate.
// d_ws layout: [0, NSLOT*DIM*4) actbuf | [+, NWAVE*4) progress (gated mode)

__device__ __forceinline__ float cvt_f16_lo(uint32_t u) {
  __half h;
  uint16_t b = (uint16_t)u;
  __builtin_memcpy(&h, &b, 2);
  return __half2float(h);
}

template<int NSLOT>
__global__ __launch_bounds__(NTH, 1) void ctrnn_kernel(
    const float* __restrict__ x,        // [TIME, DIM]
    const float* __restrict__ W,        // [DIM, DIM]
    const float* __restrict__ bias,     // [DIM]
    const float* __restrict__ initial,  // [DIM]
    float* __restrict__ out,            // [TIME, DIM]
    uint32_t* __restrict__ actbuf,
    uint32_t* __restrict__ progress)
{
  const int lane = threadIdx.x & 63;
  const int wid  = (blockIdx.x << 2) | (threadIdx.x >> 6);  // 0..511
  const int r0   = wid * RPW;

  // W fragment: 4 rows x cols [lane*32, lane*32+32), fp32 in registers.
  float wreg[4][32];
  #pragma unroll
  for (int rr = 0; rr < 4; ++rr) {
    const float4* wrow =
        reinterpret_cast<const float4*>(W + (size_t)(r0 + rr) * DIM + lane * 32);
    #pragma unroll
    for (int i = 0; i < 8; ++i) {
      const float4 w4 = wrow[i];
      wreg[rr][4*i+0] = w4.x; wreg[rr][4*i+1] = w4.y;
      wreg[rr][4*i+2] = w4.z; wreg[rr][4*i+3] = w4.w;
    }
  }

  // State: lanes 0..3 own rows r0..r0+3.
  float v = 0.f, bj = 0.f, xv = 0.f;
  if (lane < RPW) {
    const int j = r0 + lane;
    v  = initial[j];
    bj = bias[j];
    xv = x[j];
    out[j] = v;
    const float a0 = 1.0f / (1.0f + __expf(-(v + bj)));
    __half h = __float2half_rn(a0);
    uint16_t hb; __builtin_memcpy(&hb, &h, 2);
    const uint32_t e = (1u << 16) | hb;
    __hip_atomic_store(&actbuf[j], e, __ATOMIC_RELAXED, __HIP_MEMORY_SCOPE_AGENT);
  }

  uint32_t prog_seen = 0;

  for (int t = 0; t < TIME_STEPS - 1; ++t) {
    // Prefetch next x early (consumed after the dot; latency hidden).
    float xn = 0.f;
    if (lane < RPW) xn = x[(size_t)(t + 1) * DIM + r0 + lane];

    // ---- poll this lane's 32 activation entries (16 x 8B agent loads) ----
    const uint32_t needtag = (uint32_t)(t + 1);
    const uint64_t* src = reinterpret_cast<const uint64_t*>(
        actbuf + (size_t)(t % NSLOT) * DIM) + (lane << 4);
    uint64_t raw[16];
    #pragma unroll
    for (int i = 0; i < 16; ++i)
      raw[i] = __hip_atomic_load(&src[i], __ATOMIC_RELAXED, __HIP_MEMORY_SCOPE_AGENT);

    uint32_t pend = 0xFFFFu;
    do {
      uint32_t nxt = 0;
      #pragma unroll
      for (int i = 0; i < 16; ++i) {
        if (pend & (1u << i)) {
          const uint32_t lo = (uint32_t)raw[i];
          const uint32_t hi = (uint32_t)(raw[i] >> 32);
          if (((lo >> 16) != needtag) | ((hi >> 16) != needtag)) nxt |= (1u << i);
        }
      }
      pend = nxt;
      if (pend) {
        #pragma unroll
        for (int i = 0; i < 16; ++i)
          if (pend & (1u << i))
            raw[i] = __hip_atomic_load(&src[i], __ATOMIC_RELAXED, __HIP_MEMORY_SCOPE_AGENT);
      }
    } while (pend);

    // Gated mode: announce that this wave has consumed slot t (gen t+1 staged).
    if (NSLOT < TIME_STEPS) {
      if (lane == 0)
        __hip_atomic_store(&progress[wid], needtag,
                           __ATOMIC_RELAXED, __HIP_MEMORY_SCOPE_AGENT);
    }

    // ---- dot: 4 rows x 32 cols per lane, cvt fp16->f32 inline ----
    float acc0 = 0.f, acc1 = 0.f, acc2 = 0.f, acc3 = 0.f;
    #pragma unroll
    for (int i = 0; i < 16; ++i) {
      const uint32_t lo = (uint32_t)raw[i];
      const uint32_t hi = (uint32_t)(raw[i] >> 32);
      const float a0 = cvt_f16_lo(lo);
      const float a1 = cvt_f16_lo(hi);
      acc0 = fmaf(wreg[0][2*i+1], a1, fmaf(wreg[0][2*i], a0, acc0));
      acc1 = fmaf(wreg[1][2*i+1], a1, fmaf(wreg[1][2*i], a0, acc1));
      acc2 = fmaf(wreg[2][2*i+1], a1, fmaf(wreg[2][2*i], a0, acc2));
      acc3 = fmaf(wreg[3][2*i+1], a1, fmaf(wreg[3][2*i], a0, acc3));
    }
    // Wait: wreg index must cover 32 cols; entries 2i,2i+1 map to cols 2i,2i+1. OK.

    // ---- merge-reduce: 10 shuffles -> lane c (c<4) holds row c total ----
    const float y0 = __shfl_xor(acc0, 1, 64);
    const float y1 = __shfl_xor(acc1, 1, 64);
    const float y2 = __shfl_xor(acc2, 1, 64);
    const float y3 = __shfl_xor(acc3, 1, 64);
    const float m  = (lane & 1) ? (acc1 + y1) : (acc0 + y0);  // row lane&1
    const float mB = (lane & 1) ? (acc3 + y3) : (acc2 + y2);  // row 2+(lane&1)
    const float zm  = __shfl_xor(m, 2, 64);
    const float zmB = __shfl_xor(mB, 2, 64);
    float n = (lane & 2) ? (mB + zmB) : (m + zm);             // row lane&3
    n += __shfl_xor(n, 4, 64);
    n += __shfl_xor(n, 8, 64);
    n += __shfl_xor(n, 16, 64);
    n += __shfl_xor(n, 32, 64);

    // ---- WAR gate (gated mode only), amortized full-min check ----
    if (NSLOT < TIME_STEPS) {
      if (t >= NSLOT - 1) {
        const uint32_t need = (uint32_t)(t + 2 - NSLOT);
        if (need > prog_seen) {
          for (;;) {
            uint32_t mn = 0xFFFFFFFFu;
            #pragma unroll
            for (int i = 0; i < 8; ++i) {
              const uint32_t p = __hip_atomic_load(&progress[(lane << 3) + i],
                                     __ATOMIC_RELAXED, __HIP_MEMORY_SCOPE_AGENT);
              mn = p < mn ? p : mn;
            }
            uint32_t q;
            q = (uint32_t)__shfl_xor((int)mn, 1, 64);  mn = q < mn ? q : mn;
            q = (uint32_t)__shfl_xor((int)mn, 2, 64);  mn = q < mn ? q : mn;
            q = (uint32_t)__shfl_xor((int)mn, 4, 64);  mn = q < mn ? q : mn;
            q = (uint32_t)__shfl_xor((int)mn, 8, 64);  mn = q < mn ? q : mn;
            q = (uint32_t)__shfl_xor((int)mn, 16, 64); mn = q < mn ? q : mn;
            q = (uint32_t)__shfl_xor((int)mn, 32, 64); mn = q < mn ? q : mn;
            if (mn >= need) { prog_seen = mn; break; }
          }
        }
      }
    }

    // ---- state update + out + publish (lanes 0..3) ----
    if (lane < RPW) {
      v  = 0.9f * v + 0.1f * (n + xv);
      xv = xn;
      out[(size_t)(t + 1) * DIM + r0 + lane] = v;
      const float a = 1.0f / (1.0f + __expf(-(v + bj)));
      __half h = __float2half_rn(a);
      uint16_t hb; __builtin_memcpy(&hb, &h, 2);
      const uint32_t e = ((uint32_t)(t + 2) << 16) | hb;
      __hip_atomic_store(&actbuf[(size_t)((t + 1) % NSLOT) * DIM + r0 + lane], e,
                         __ATOMIC_RELAXED, __HIP_MEMORY_SCOPE_AGENT);
    }
  }
}

extern "C" void kernel_launch(void* const* d_in, const int* in_sizes, int n_in,
                              void* d_out, int out_size, void* d_ws, size_t ws_size,
                              hipStream_t stream) {
  const float* x       = (const float*)d_in[0];
  const float* W       = (const float*)d_in[1];
  const float* bias    = (const float*)d_in[2];
  const float* initial = (const float*)d_in[3];
  float* out           = (float*)d_out;

  uint32_t* actbuf = (uint32_t*)d_ws;

  const size_t need_full = (size_t)TIME_STEPS * DIM * 4 + NWAVE * 4;
  const size_t need_64   = (size_t)64 * DIM * 4 + NWAVE * 4;

  void* kfun;
  size_t actbytes;
  if (ws_size >= need_full)    { kfun = (void*)ctrnn_kernel<TIME_STEPS>; actbytes = (size_t)TIME_STEPS * DIM * 4; }
  else if (ws_size >= need_64) { kfun = (void*)ctrnn_kernel<64>;         actbytes = (size_t)64 * DIM * 4; }
  else                         { kfun = (void*)ctrnn_kernel<8>;          actbytes = (size_t)8 * DIM * 4; }

  uint32_t* progress = (uint32_t*)((char*)d_ws + actbytes);

  // Tags are generation counters: clear every call (honest re-timing, no
  // cross-replay state). Memset is graph-capture safe.
  hipMemsetAsync(d_ws, 0, actbytes + NWAVE * 4, stream);

  void* args[] = { (void*)&x, (void*)&W, (void*)&bias, (void*)&initial,
                   (void*)&out, (void*)&actbuf, (void*)&progress };
  hipLaunchCooperativeKernel(kfun, dim3(NWG), dim3(NTH), args, 0, stream);
}

// Round 4
// 12108.446 us; speedup vs baseline: 3.1879x; 3.1879x over previous
//
#include <hip/hip_runtime.h>
#include <hip/hip_fp16.h>
#include <stdint.h>

#define TIME_STEPS 4096
#define DIM        2048
#define NWG        128
#define NTH        256
#define PITCH      132   // floats; 128 + 4 pad

typedef uint32_t u32x4 __attribute__((ext_vector_type(4)));

// actbuf entry: u32 = (tag16 << 16) | fp16bits(act); slot t%NSLOT holds gen t
// (tag = t+1, max 4097 fits 16 bits).
// d_ws: [0, NSLOT*DIM*4) ring | [+, NWG*4) progress[wg] = last consumed gen + 1

__device__ __forceinline__ float h2f(uint32_t e) {
  __half h;
  uint16_t b = (uint16_t)e;
  __builtin_memcpy(&h, &b, 2);
  return __half2float(h);
}

// Two 16B agent-scope loads + ONE waitcnt (batched; served at the LLC).
#define POLL_QUADS(q0, q1, src)                                        \
  asm volatile("global_load_dwordx4 %0, %2, off sc1\n\t"               \
               "global_load_dwordx4 %1, %3, off sc1\n\t"               \
               "s_waitcnt vmcnt(0)"                                    \
               : "=&v"(q0), "=&v"(q1)                                  \
               : "v"(src), "v"(src + 4)                                \
               : "memory")

template<int NSLOT>
__global__ __launch_bounds__(NTH, 1) void ctrnn_kernel(
    const float* __restrict__ x,        // [TIME, DIM]
    const float* __restrict__ W,        // [DIM, DIM]
    const float* __restrict__ bias,     // [DIM]
    const float* __restrict__ initial,  // [DIM]
    float* __restrict__ out,            // [TIME, DIM]
    uint32_t* __restrict__ actbuf,
    uint32_t* __restrict__ progress)
{
  const int tid = threadIdx.x;
  const int wg  = blockIdx.x;
  const int s   = tid & 15;      // k-slice (0..15), 128 cols each
  const int r   = tid >> 4;      // row in WG (0..15)
  const int j   = wg * 16 + r;
  const bool owner = (s == 0);

  __shared__ float act_lds[2][16 * PITCH];

  // W[j][s*128 .. +128) in registers for the whole kernel.
  float4 wreg[32];
  {
    const float4* wrow = reinterpret_cast<const float4*>(W + (size_t)j * DIM + s * 128);
    #pragma unroll
    for (int i = 0; i < 32; ++i) wreg[i] = wrow[i];
  }

  float v = 0.f, bj = 0.f, xv = 0.f;
  if (owner) {
    v  = initial[j];
    bj = bias[j];
    xv = x[j];
    out[j] = v;
    const float a0 = 1.0f / (1.0f + __expf(-(v + bj)));
    __half h = __float2half_rn(a0);
    uint16_t hb; __builtin_memcpy(&hb, &h, 2);
    const uint32_t e = (1u << 16) | hb;
    __hip_atomic_store(&actbuf[j], e, __ATOMIC_RELAXED, __HIP_MEMORY_SCOPE_AGENT);
  }

  uint32_t prog_seen = 0;

  for (int t = 0; t < TIME_STEPS - 1; ++t) {
    const int b = t & 1;

    // Early x prefetch (consumed after the dot; latency hidden under poll).
    float xn = 0.f;
    if (owner) xn = x[(size_t)(t + 1) * DIM + j];

    // ---- poll slot t: this thread's 8 entries (32B, lane-coalesced) ----
    const uint32_t needtag = (uint32_t)(t + 1);
    const uint32_t* src = actbuf + (size_t)(t & (NSLOT - 1)) * DIM + tid * 8;
    u32x4 q0, q1;
    POLL_QUADS(q0, q1, src);
    for (;;) {
      const bool ok =
          ((q0[0] >> 16) >= needtag) & ((q0[1] >> 16) >= needtag) &
          ((q0[2] >> 16) >= needtag) & ((q0[3] >> 16) >= needtag) &
          ((q1[0] >> 16) >= needtag) & ((q1[1] >> 16) >= needtag) &
          ((q1[2] >> 16) >= needtag) & ((q1[3] >> 16) >= needtag);
      if (ok) break;
      POLL_QUADS(q0, q1, src);
    }

    // ---- stage to LDS (fp32), entry k=tid*8+i -> slice r, offset s*8+i ----
    {
      float* dst = &act_lds[b][r * PITCH + s * 8];
      dst[0] = h2f(q0[0]); dst[1] = h2f(q0[1]);
      dst[2] = h2f(q0[2]); dst[3] = h2f(q0[3]);
      dst[4] = h2f(q1[0]); dst[5] = h2f(q1[1]);
      dst[6] = h2f(q1[2]); dst[7] = h2f(q1[3]);
    }

    __syncthreads();  // buf[b] staged; WAR vs t+2 stores is covered by t+1's barrier

    if (tid == 0)
      __hip_atomic_store(&progress[wg], needtag,
                         __ATOMIC_RELAXED, __HIP_MEMORY_SCOPE_AGENT);

    // ---- partial dot over slice s ----
    float4 acc = {0.f, 0.f, 0.f, 0.f};
    const float4* ap = reinterpret_cast<const float4*>(&act_lds[b][s * PITCH]);
    #pragma unroll
    for (int i = 0; i < 32; ++i) {
      const float4 a4 = ap[i];
      acc.x = fmaf(wreg[i].x, a4.x, acc.x);
      acc.y = fmaf(wreg[i].y, a4.y, acc.y);
      acc.z = fmaf(wreg[i].z, a4.z, acc.z);
      acc.w = fmaf(wreg[i].w, a4.w, acc.w);
    }
    float p = (acc.x + acc.y) + (acc.z + acc.w);
    p += __shfl_xor(p, 1, 64);
    p += __shfl_xor(p, 2, 64);
    p += __shfl_xor(p, 4, 64);
    p += __shfl_xor(p, 8, 64);

    // ---- WAR gate: before publishing gen t+1 over slot (t+1)%NSLOT, all WGs
    //      must have consumed gen t+1-NSLOT. Fires every ~NSLOT-1 steps. ----
    if (t >= NSLOT - 1) {
      const uint32_t need = (uint32_t)(t + 2 - NSLOT);
      if (need > prog_seen) {
        const int lane = tid & 63;
        for (;;) {
          const uint32_t pa = __hip_atomic_load(&progress[lane],
                                  __ATOMIC_RELAXED, __HIP_MEMORY_SCOPE_AGENT);
          const uint32_t pb = __hip_atomic_load(&progress[lane + 64],
                                  __ATOMIC_RELAXED, __HIP_MEMORY_SCOPE_AGENT);
          uint32_t mn = pa < pb ? pa : pb;
          uint32_t q;
          q = (uint32_t)__shfl_xor((int)mn, 1, 64);  mn = q < mn ? q : mn;
          q = (uint32_t)__shfl_xor((int)mn, 2, 64);  mn = q < mn ? q : mn;
          q = (uint32_t)__shfl_xor((int)mn, 4, 64);  mn = q < mn ? q : mn;
          q = (uint32_t)__shfl_xor((int)mn, 8, 64);  mn = q < mn ? q : mn;
          q = (uint32_t)__shfl_xor((int)mn, 16, 64); mn = q < mn ? q : mn;
          q = (uint32_t)__shfl_xor((int)mn, 32, 64); mn = q < mn ? q : mn;
          if (mn >= need) { prog_seen = mn; break; }
        }
      }
    }

    // ---- state update + out + publish (16 owners, one 64B line per WG) ----
    if (owner) {
      v  = 0.9f * v + 0.1f * (p + xv);
      xv = xn;
      out[(size_t)(t + 1) * DIM + j] = v;
      const float a = 1.0f / (1.0f + __expf(-(v + bj)));
      __half h = __float2half_rn(a);
      uint16_t hb; __builtin_memcpy(&hb, &h, 2);
      const uint32_t e = ((uint32_t)(t + 2) << 16) | hb;
      __hip_atomic_store(&actbuf[(size_t)((t + 1) & (NSLOT - 1)) * DIM + j], e,
                         __ATOMIC_RELAXED, __HIP_MEMORY_SCOPE_AGENT);
    }
  }
}

extern "C" void kernel_launch(void* const* d_in, const int* in_sizes, int n_in,
                              void* d_out, int out_size, void* d_ws, size_t ws_size,
                              hipStream_t stream) {
  const float* x       = (const float*)d_in[0];
  const float* W       = (const float*)d_in[1];
  const float* bias    = (const float*)d_in[2];
  const float* initial = (const float*)d_in[3];
  float* out           = (float*)d_out;

  uint32_t* actbuf = (uint32_t*)d_ws;

  const size_t need32 = (size_t)32 * DIM * 4 + NWG * 4;
  void* kfun;
  size_t actbytes;
  if (ws_size >= need32) { kfun = (void*)ctrnn_kernel<32>; actbytes = (size_t)32 * DIM * 4; }
  else                   { kfun = (void*)ctrnn_kernel<8>;  actbytes = (size_t)8  * DIM * 4; }

  uint32_t* progress = (uint32_t*)((char*)d_ws + actbytes);

  // Tags are generation counters — clear every call (graph-capture safe).
  hipMemsetAsync(d_ws, 0, actbytes + NWG * 4, stream);

  void* args[] = { (void*)&x, (void*)&W, (void*)&bias, (void*)&initial,
                   (void*)&out, (void*)&actbuf, (void*)&progress };
  hipLaunchCooperativeKernel(kfun, dim3(NWG), dim3(NTH), args, 0, stream);
}

// Round 5
// 9834.393 us; speedup vs baseline: 3.9251x; 1.2312x over previous
//
#include <hip/hip_runtime.h>
#include <hip/hip_fp16.h>
#include <stdint.h>

#define TIME_STEPS 4096
#define DIM        2048
#define NWG        256
#define NTH        128
#define NWAVE      512   // (NWG*NTH)/64, 4 rows per wave
#define RPW        4

typedef uint32_t u32x4 __attribute__((ext_vector_type(4)));
typedef _Float16 h2f16 __attribute__((ext_vector_type(2)));

// actbuf entry: u32 = (tag16 << 16) | fp16bits(act); slot t%NSLOT holds gen t
// (tag = t+1 <= 4097, fits 16 bits). All-valid check: min over dwords >= tag<<16
// (act bits are the low 16 -> cannot make a fresh dword compare below).
// d_ws: [0, NSLOT*DIM*4) ring | [+, NWAVE*4) progress[wave] = last consumed gen

__device__ __forceinline__ uint32_t umin32(uint32_t a, uint32_t b) { return a < b ? a : b; }

__device__ __forceinline__ float dot2f(uint32_t packed, h2f16 w, float acc) {
#if __has_builtin(__builtin_amdgcn_fdot2)
  return __builtin_amdgcn_fdot2(__builtin_bit_cast(h2f16, packed), w, acc, false);
#else
  h2f16 a = __builtin_bit_cast(h2f16, packed);
  acc = fmaf((float)a.x, (float)w.x, acc);
  return fmaf((float)a.y, (float)w.y, acc);
#endif
}

template<int NSLOT>
__global__ __launch_bounds__(NTH, 1) void ctrnn_kernel(
    const float* __restrict__ x,        // [TIME, DIM]
    const float* __restrict__ W,        // [DIM, DIM]
    const float* __restrict__ bias,     // [DIM]
    const float* __restrict__ initial,  // [DIM]
    float* __restrict__ out,            // [TIME, DIM]
    uint32_t* __restrict__ actbuf,
    uint32_t* __restrict__ progress)
{
  const int lane = threadIdx.x & 63;
  const int wid  = (blockIdx.x << 1) | (threadIdx.x >> 6);  // 0..511
  const int s    = lane >> 2;        // 16 col-slices of 128
  const int rr   = lane & 3;         // sub-offset within each 64B line
  const int row0 = wid * RPW;
  // This thread's 32 cols: {s*128 + rr*4 + k*16 + 0..3, k=0..7}
  const int cb   = s * 128 + rr * 4;

  // W packed fp16x2: 4 rows x this thread's 32 cols = 64 VGPRs.
  h2f16 w2[4][16];
  #pragma unroll
  for (int m = 0; m < 4; ++m) {
    const float* wr = W + (size_t)(row0 + m) * DIM + cb;
    #pragma unroll
    for (int k = 0; k < 8; ++k) {
      w2[m][2*k]   = h2f16{(_Float16)wr[k*16 + 0], (_Float16)wr[k*16 + 1]};
      w2[m][2*k+1] = h2f16{(_Float16)wr[k*16 + 2], (_Float16)wr[k*16 + 3]};
    }
  }

  // State: lanes 0..3 own rows row0..row0+3.
  float v = 0.f, bj = 0.f, xv = 0.f;
  if (lane < RPW) {
    const int j = row0 + lane;
    v  = initial[j];
    bj = bias[j];
    xv = x[j];
    out[j] = v;
    const float a0 = 1.0f / (1.0f + __expf(-(v + bj)));
    __half h = __float2half_rn(a0);
    uint16_t hb; __builtin_memcpy(&hb, &h, 2);
    __hip_atomic_store(&actbuf[j], (1u << 16) | hb,
                       __ATOMIC_RELAXED, __HIP_MEMORY_SCOPE_AGENT);
  }

  uint32_t prog_seen = 0;

  for (int t = 0; t < TIME_STEPS - 1; ++t) {
    // x prefetch: issued before polls; first poll's vmcnt absorbs its latency.
    float xn = 0.f;
    if (lane < RPW) xn = x[(size_t)(t + 1) * DIM + row0 + lane];

    const uint32_t needtag = (uint32_t)(t + 1);
    const uint32_t thresh  = needtag << 16;
    const uint32_t* src = actbuf + (size_t)(t & (NSLOT - 1)) * DIM + cb;

    // ---- wave-synchronized poll: 8 dwordx4, every 64B line read exactly once
    //      per wave per round (lanes rr=0..3 cover the 4 quads of line k,s) ----
    u32x4 q[8];
    for (;;) {
      asm volatile(
        "global_load_dwordx4 %0, %8, off sc1\n\t"
        "global_load_dwordx4 %1, %8, off offset:64 sc1\n\t"
        "global_load_dwordx4 %2, %8, off offset:128 sc1\n\t"
        "global_load_dwordx4 %3, %8, off offset:192 sc1\n\t"
        "global_load_dwordx4 %4, %8, off offset:256 sc1\n\t"
        "global_load_dwordx4 %5, %8, off offset:320 sc1\n\t"
        "global_load_dwordx4 %6, %8, off offset:384 sc1\n\t"
        "global_load_dwordx4 %7, %8, off offset:448 sc1\n\t"
        "s_waitcnt vmcnt(0)"
        : "=&v"(q[0]), "=&v"(q[1]), "=&v"(q[2]), "=&v"(q[3]),
          "=&v"(q[4]), "=&v"(q[5]), "=&v"(q[6]), "=&v"(q[7])
        : "v"(src)
        : "memory");
      __builtin_amdgcn_sched_barrier(0);

      uint32_t mn = 0xFFFFFFFFu;
      #pragma unroll
      for (int k = 0; k < 8; ++k)
        mn = umin32(mn, umin32(umin32(q[k][0], q[k][1]),
                               umin32(q[k][2], q[k][3])));
      if (__all((int)(mn >= thresh))) break;
    }

    // Announce consumption (producers gate ring reuse on this).
    if (lane == 0)
      __hip_atomic_store(&progress[wid], needtag,
                         __ATOMIC_RELAXED, __HIP_MEMORY_SCOPE_AGENT);

    // ---- dot: 4 rows x 32 cols per thread; 16 perm + 64 fdot2 ----
    float a0 = 0.f, a1 = 0.f, a2 = 0.f, a3 = 0.f;
    #pragma unroll
    for (int k = 0; k < 8; ++k) {
      const uint32_t lo = __builtin_amdgcn_perm(q[k][1], q[k][0], 0x05040100u);
      const uint32_t hi = __builtin_amdgcn_perm(q[k][3], q[k][2], 0x05040100u);
      a0 = dot2f(lo, w2[0][2*k], a0); a0 = dot2f(hi, w2[0][2*k+1], a0);
      a1 = dot2f(lo, w2[1][2*k], a1); a1 = dot2f(hi, w2[1][2*k+1], a1);
      a2 = dot2f(lo, w2[2][2*k], a2); a2 = dot2f(hi, w2[2][2*k+1], a2);
      a3 = dot2f(lo, w2[3][2*k], a3); a3 = dot2f(hi, w2[3][2*k+1], a3);
    }

    // ---- merge-reduce: lane l ends with row (l&3) total ----
    const float t0 = a0 + __shfl_xor(a0, 1, 64);
    const float t1 = a1 + __shfl_xor(a1, 1, 64);
    const float t2 = a2 + __shfl_xor(a2, 1, 64);
    const float t3 = a3 + __shfl_xor(a3, 1, 64);
    const float m01 = (lane & 1) ? t1 : t0;
    const float m23 = (lane & 1) ? t3 : t2;
    const float u01 = m01 + __shfl_xor(m01, 2, 64);
    const float u23 = m23 + __shfl_xor(m23, 2, 64);
    float p = (lane & 2) ? u23 : u01;
    p += __shfl_xor(p, 4, 64);
    p += __shfl_xor(p, 8, 64);
    p += __shfl_xor(p, 16, 64);
    p += __shfl_xor(p, 32, 64);

    // ---- WAR gate: publishing gen t+1 over slot (t+1)%NSLOT needs all waves
    //      to have consumed gen t+1-NSLOT. Fires ~every NSLOT-1 steps. ----
    if (t >= NSLOT - 1) {
      const uint32_t need = (uint32_t)(t + 2 - NSLOT);
      if (need > prog_seen) {
        for (;;) {
          uint32_t mn = 0xFFFFFFFFu;
          #pragma unroll
          for (int i = 0; i < 8; ++i)
            mn = umin32(mn, __hip_atomic_load(&progress[lane + 64*i],
                              __ATOMIC_RELAXED, __HIP_MEMORY_SCOPE_AGENT));
          uint32_t qq;
          qq = (uint32_t)__shfl_xor((int)mn, 1, 64);  mn = umin32(mn, qq);
          qq = (uint32_t)__shfl_xor((int)mn, 2, 64);  mn = umin32(mn, qq);
          qq = (uint32_t)__shfl_xor((int)mn, 4, 64);  mn = umin32(mn, qq);
          qq = (uint32_t)__shfl_xor((int)mn, 8, 64);  mn = umin32(mn, qq);
          qq = (uint32_t)__shfl_xor((int)mn, 16, 64); mn = umin32(mn, qq);
          qq = (uint32_t)__shfl_xor((int)mn, 32, 64); mn = umin32(mn, qq);
          if (mn >= need) { prog_seen = mn; break; }
        }
      }
    }

    // ---- state update + out + publish (lanes 0..3, 16B/wave, one line/4 waves) ----
    if (lane < RPW) {
      v  = 0.9f * v + 0.1f * (p + xv);
      xv = xn;
      out[(size_t)(t + 1) * DIM + row0 + lane] = v;
      const float a = 1.0f / (1.0f + __expf(-(v + bj)));
      __half h = __float2half_rn(a);
      uint16_t hb; __builtin_memcpy(&hb, &h, 2);
      const uint32_t e = ((uint32_t)(t + 2) << 16) | hb;
      __hip_atomic_store(&actbuf[(size_t)((t + 1) & (NSLOT - 1)) * DIM + row0 + lane], e,
                         __ATOMIC_RELAXED, __HIP_MEMORY_SCOPE_AGENT);
    }
  }
}

extern "C" void kernel_launch(void* const* d_in, const int* in_sizes, int n_in,
                              void* d_out, int out_size, void* d_ws, size_t ws_size,
                              hipStream_t stream) {
  const float* x       = (const float*)d_in[0];
  const float* W       = (const float*)d_in[1];
  const float* bias    = (const float*)d_in[2];
  const float* initial = (const float*)d_in[3];
  float* out           = (float*)d_out;

  uint32_t* actbuf = (uint32_t*)d_ws;

  const size_t need32 = (size_t)32 * DIM * 4 + NWAVE * 4;
  void* kfun;
  size_t actbytes;
  if (ws_size >= need32) { kfun = (void*)ctrnn_kernel<32>; actbytes = (size_t)32 * DIM * 4; }
  else                   { kfun = (void*)ctrnn_kernel<8>;  actbytes = (size_t)8  * DIM * 4; }

  uint32_t* progress = (uint32_t*)((char*)d_ws + actbytes);

  // Tags are generation counters — clear every call (graph-capture safe).
  hipMemsetAsync(d_ws, 0, actbytes + NWAVE * 4, stream);

  void* args[] = { (void*)&x, (void*)&W, (void*)&bias, (void*)&initial,
                   (void*)&out, (void*)&actbuf, (void*)&progress };
  hipLaunchCooperativeKernel(kfun, dim3(NWG), dim3(NTH), args, 0, stream);
}